// Round 16
// baseline (344.778 us; speedup 1.0000x reference)
//
#include <hip/hip_runtime.h>
#include <hip/hip_bf16.h>

typedef int i32x4 __attribute__((ext_vector_type(4)));

#define N_TOKENS 32768
#define N_CODES 4096
#define DIM 1280
#define NT 20            // K-tiles of 64 (i8)
#define BUFSZ 32768      // A 16KB + B 16KB per K-tile buffer

__device__ __forceinline__ void load_lds16(const void* g, void* l) {
    __builtin_amdgcn_global_load_lds(
        (const __attribute__((address_space(1))) unsigned int*)g,
        (__attribute__((address_space(3))) unsigned int*)l,
        16, 0, 0);
}

// ---------------------------------------------------------------------------
// Kernel 0: per-row symmetric int8 quantize (RNE), X and E fused (r11-r15
// verified). Exact-int dot => score err sigma ~3.4e-4; refine thr 3e-3.
// At HBM floor: 236 MB moved ~ 38 us.
// ---------------------------------------------------------------------------
__global__ __launch_bounds__(256) void quantize_i8_kernel(
    const float* __restrict__ X, const float* __restrict__ E,
    signed char* __restrict__ Xq, signed char* __restrict__ Eq,
    float* __restrict__ sxs, float* __restrict__ ses)
{
    int row = blockIdx.x * 4 + (threadIdx.x >> 6);
    const float* src;
    signed char* dst;
    float* scale;
    if (row < N_TOKENS) {
        src = X + (size_t)row * DIM; dst = Xq + (size_t)row * DIM; scale = sxs + row;
    } else {
        int r = row - N_TOKENS;
        if (r >= N_CODES) return;
        src = E + (size_t)r * DIM; dst = Eq + (size_t)r * DIM; scale = ses + r;
    }
    int lane = threadIdx.x & 63;
    const float4* s4 = (const float4*)src;
    float4 v[5];
    float amax = 0.f;
    #pragma unroll
    for (int j = 0; j < 5; ++j) {
        v[j] = s4[j * 64 + lane];
        amax = fmaxf(amax, fmaxf(fmaxf(fabsf(v[j].x), fabsf(v[j].y)),
                                 fmaxf(fabsf(v[j].z), fabsf(v[j].w))));
    }
    #pragma unroll
    for (int d = 1; d < 64; d <<= 1) amax = fmaxf(amax, __shfl_xor(amax, d));
    amax = fmaxf(amax, 1e-20f);
    float inv = 127.0f / amax;
    int* d4 = (int*)dst;
    #pragma unroll
    for (int j = 0; j < 5; ++j) {
        int q0 = (int)rintf(v[j].x * inv), q1 = (int)rintf(v[j].y * inv);
        int q2 = (int)rintf(v[j].z * inv), q3 = (int)rintf(v[j].w * inv);
        d4[j * 64 + lane] = (q0 & 0xFF) | ((q1 & 0xFF) << 8) |
                            ((q2 & 0xFF) << 16) | ((q3 & 0xFF) << 24);
    }
    if (lane == 0) *scale = amax * (1.0f / 127.0f);
}

// ---------------------------------------------------------------------------
// Kernel 1: i8 GEMM 256x256, 16 waves (4x4, 64x64 wave tile), BK=64 —
// r6/r12 champion schedule, SETPRIO REMOVED (m190: s_setprio hurts
// lockstep non-phase-split GEMMs; T5 requires wave role diversity our
// barrier-locked structure lacks). Otherwise byte-identical to r12/r13.
// Ledger: prologue STAGE(0,1,2) [6 pending], vmcnt(4) certifies tile 0;
// iter t: STAGE(t+3); COMPUTE(t); vmcnt(4) certifies t+1; barrier.
// Overwrite: STAGE(t+3) -> buf[(t+3)&3], last read iter t-1 pre-barrier.
// Closed model: 3490 cyc/iter = 1536 LDS-read (4x frag reuse at 64x64 wave
// tiles) + 1306 MFMA + ~650 stage/sync, additive; wave-tile growth to cut
// reuse needs acc > 128 regs -> 2 waves/SIMD (r5/r9: worse). 9 schedule
// variants (r7-r15) all neutral-or-regress vs this structure.
// ---------------------------------------------------------------------------
__global__ __launch_bounds__(1024, 4) void gemm_argmax_kernel(
    const signed char* __restrict__ Xq, const signed char* __restrict__ Eq,
    const float* __restrict__ sx, const float* __restrict__ se,
    unsigned* __restrict__ pkeys)
{
    __shared__ __align__(16) char lds[4 * BUFSZ];   // 128 KB

    int bid = blockIdx.x;
    int xcd = bid & 7, i = bid >> 3;          // i in 0..255 per XCD
    int cb0 = (xcd << 1) + (i & 1);           // adjacent pair shares rb (r11)
    int rb = i >> 1;                          // 0..127
    int row0 = rb << 8, col0 = cb0 << 8;

    int tid = threadIdx.x;
    int wid = tid >> 6, lane = tid & 63;
    int wm = wid >> 2, wn = wid & 3;          // 4x4 wave grid, tile 64x64
    int lr = lane & 15, g = lane >> 4;

    int slot = (((lr & 1) << 2) + g) ^ ((lr >> 1) & 7);
    int aoff = ((wm << 5) + (lr >> 1)) * 128 + slot * 16;            // A region
    int boff = 16384 + ((wn << 5) + (lr >> 1)) * 128 + slot * 16;    // B region

    i32x4 acc[4][4] = {};

    auto STAGE = [&](int t) {
        int base = (t & 3) * BUFSZ;
        int k0 = t << 6;                     // byte k-offset (i8)
        int f = tid;                         // slot 0..1023
        int rp = f >> 3, c = f & 7;
        int cp = c ^ (rp & 7);               // pre-swizzled source chunk
        int gr = (rp << 1) + (cp >> 2);      // global row in tile
        int kc = k0 + ((cp & 3) << 4);       // 16B k-chunk
        load_lds16(Xq + (size_t)(row0 + gr) * DIM + kc, lds + base + (f << 4));
        load_lds16(Eq + (size_t)(col0 + gr) * DIM + kc, lds + base + 16384 + (f << 4));
    };

    auto COMPUTE = [&](int t) {
        int base = (t & 3) * BUFSZ;
        const char* pA = lds + base + aoff;
        const char* pB = lds + base + boff;
        i32x4 a[4], b[4];
        #pragma unroll
        for (int m = 0; m < 4; ++m) a[m] = *(const i32x4*)(pA + (m << 10));
        #pragma unroll
        for (int n = 0; n < 4; ++n) b[n] = *(const i32x4*)(pB + (n << 10));
        #pragma unroll
        for (int m = 0; m < 4; ++m)
            #pragma unroll
            for (int n = 0; n < 4; ++n)
                acc[m][n] = __builtin_amdgcn_mfma_i32_16x16x64_i8(
                    a[m], b[n], acc[m][n], 0, 0, 0);
    };

    STAGE(0); STAGE(1); STAGE(2);                 // 6 outstanding
    asm volatile("s_waitcnt vmcnt(4)" ::: "memory");
    __builtin_amdgcn_s_barrier();
    __builtin_amdgcn_sched_barrier(0);

    #pragma unroll 1
    for (int t = 0; t < NT - 3; ++t) {
        STAGE(t + 3);
        COMPUTE(t);
        asm volatile("s_waitcnt vmcnt(4)" ::: "memory");
        __builtin_amdgcn_s_barrier();
        __builtin_amdgcn_sched_barrier(0);
    }
    COMPUTE(NT - 3);
    asm volatile("s_waitcnt vmcnt(2)" ::: "memory");
    __builtin_amdgcn_s_barrier();
    __builtin_amdgcn_sched_barrier(0);
    COMPUTE(NT - 2);
    asm volatile("s_waitcnt vmcnt(0)" ::: "memory");
    __builtin_amdgcn_s_barrier();
    __builtin_amdgcn_sched_barrier(0);
    COMPUTE(NT - 1);
    __syncthreads();   // drain; LDS reused for epilogue merge

    // ---- dequant + fused top-2 argmax epilogue (r6-r15 verified) ----
    float se_l[4];
    #pragma unroll
    for (int n = 0; n < 4; ++n)
        se_l[n] = se[col0 + (wn << 6) + (n << 4) + lr];

    uint2* lk2 = (uint2*)lds;   // [256 rows][4 wn]
    #pragma unroll
    for (int m = 0; m < 4; ++m) {
        #pragma unroll
        for (int r = 0; r < 4; ++r) {
            int row = (wm << 6) + (m << 4) + (g << 2) + r;
            float fx = sx[row0 + row];
            unsigned b1 = 0, b2 = 0;
            #pragma unroll
            for (int n = 0; n < 4; ++n) {
                float s = (float)acc[m][n][r] * (fx * se_l[n]);
                int cib = ((wn & 1) << 6) + (n << 4) + lr;   // col in 128-block
                unsigned u = __float_as_uint(s);
                u = (u & 0x80000000u) ? ~u : (u | 0x80000000u);
                unsigned key = (u & 0xFFFFFF80u) | (unsigned)(127 - cib);
                if (key > b1) { b2 = b1; b1 = key; }
                else if (key > b2) b2 = key;
            }
            #pragma unroll
            for (int d = 1; d < 16; d <<= 1) {
                unsigned o1 = __shfl_xor(b1, d), o2 = __shfl_xor(b2, d);
                if (o1 > b1) { b2 = (b1 > o2) ? b1 : o2; b1 = o1; }
                else if (o1 > b2) b2 = o1;
            }
            if (lr == 0) {
                uint2 v; v.x = b1; v.y = b2;
                lk2[(row << 2) + wn] = v;
            }
        }
    }
    __syncthreads();
    if (tid < 512) {
        int row = tid >> 1, h = tid & 1;
        uint2 p0 = lk2[(row << 2) + (h << 1)];
        uint2 p1 = lk2[(row << 2) + (h << 1) + 1];
        unsigned b1 = p0.x, b2 = p0.y;
        if (p1.x > b1) { b2 = (b1 > p1.y) ? b1 : p1.y; b1 = p1.x; }
        else if (p1.x > b2) b2 = p1.x;
        uint2 out; out.x = b1; out.y = b2;
        *(uint2*)&pkeys[((size_t)(row0 + row) << 6) + (((cb0 << 1) + h) << 1)] = out;
    }
}

// ---------------------------------------------------------------------------
// Kernel 2: fused exact fp64 refine + gather + loss partial. 4 tokens per
// 256-thread block (r13-verified); single-candidate fast path (r11-verified).
// Near HBM floor: ~344 MB moved ~ 55 us.
// ---------------------------------------------------------------------------
__global__ __launch_bounds__(256) void refine_gather_kernel(
    const float* __restrict__ X, const float* __restrict__ E,
    const unsigned* __restrict__ pkeys, float* __restrict__ outq,
    float* __restrict__ outidx, float* __restrict__ sums)
{
    int token = blockIdx.x * 4 + (threadIdx.x >> 6);
    int lane = threadIdx.x & 63;
    unsigned k = pkeys[((size_t)token << 6) + lane];
    unsigned m = k & 0xFFFFFF80u;
    float s = __uint_as_float((m & 0x80000000u) ? (m & 0x7FFFFFFFu) : ~m);
    float smax = s;
    #pragma unroll
    for (int d = 1; d < 64; d <<= 1) smax = fmaxf(smax, __shfl_xor(smax, d));
    bool cand = s >= smax - 3e-3f;
    unsigned long long ball = __ballot(cand);

    const float4* x4 = (const float4*)(X + (size_t)token * DIM);
    float4 xv[5];
    #pragma unroll
    for (int j = 0; j < 5; ++j) xv[j] = x4[j * 64 + lane];

    int best_i;
    if (__popcll(ball) == 1) {
        int src = __ffsll(ball) - 1;
        unsigned ck = __shfl(k, src);
        best_i = ((src >> 1) << 7) + (127 - (int)(ck & 127u));
    } else {
        double best_s = -1.0e300;
        best_i = 0x7FFFFFFF;
        while (ball) {
            int src = __ffsll(ball) - 1;
            ball &= ball - 1;
            unsigned ck = __shfl(k, src);
            int cidx = ((src >> 1) << 7) + (127 - (int)(ck & 127u));
            const float4* e4 = (const float4*)(E + (size_t)cidx * DIM);
            double d = 0.0, ee = 0.0;
            #pragma unroll
            for (int j = 0; j < 5; ++j) {
                float4 ev = e4[j * 64 + lane];
                d += (double)xv[j].x * (double)ev.x + (double)xv[j].y * (double)ev.y
                   + (double)xv[j].z * (double)ev.z + (double)xv[j].w * (double)ev.w;
                ee += (double)ev.x * (double)ev.x + (double)ev.y * (double)ev.y
                    + (double)ev.z * (double)ev.z + (double)ev.w * (double)ev.w;
            }
            #pragma unroll
            for (int dd = 1; dd < 64; dd <<= 1) {
                d += __shfl_xor(d, dd);
                ee += __shfl_xor(ee, dd);
            }
            double sc = 2.0 * d - ee;
            if (sc > best_s || (sc == best_s && cidx < best_i)) { best_s = sc; best_i = cidx; }
        }
    }

    const float4* e4 = (const float4*)(E + (size_t)best_i * DIM);
    float4* o4 = (float4*)(outq + (size_t)token * DIM);
    float local = 0.0f;
    #pragma unroll
    for (int j = 0; j < 5; ++j) {
        float4 q = e4[j * 64 + lane];
        o4[j * 64 + lane] = q;
        float dx = xv[j].x - q.x, dy = xv[j].y - q.y;
        float dz = xv[j].z - q.z, dw = xv[j].w - q.w;
        local += dx * dx + dy * dy + dz * dz + dw * dw;
    }
    #pragma unroll
    for (int d = 1; d < 64; d <<= 1) local += __shfl_xor(local, d);
    if (lane == 0) {
        sums[token] = local;
        outidx[token] = (float)best_i;
    }
}

// ---------------------------------------------------------------------------
// Kernel 3a/3b: two-stage deterministic loss reduction (r13-verified).
// ---------------------------------------------------------------------------
__global__ __launch_bounds__(256) void loss_partial_kernel(
    const float* __restrict__ sums, double* __restrict__ partial)
{
    __shared__ double red[4];
    int t = threadIdx.x;
    double s = (double)sums[blockIdx.x * 256 + t];
    #pragma unroll
    for (int d = 1; d < 64; d <<= 1) s += __shfl_xor(s, d);
    if ((t & 63) == 0) red[t >> 6] = s;
    __syncthreads();
    if (t == 0) partial[blockIdx.x] = (red[0] + red[1]) + (red[2] + red[3]);
}

__global__ __launch_bounds__(128) void loss_final_kernel(
    const double* __restrict__ partial, float* __restrict__ out_loss)
{
    __shared__ double red[2];
    int t = threadIdx.x;
    double s = partial[t];
    #pragma unroll
    for (int d = 1; d < 64; d <<= 1) s += __shfl_xor(s, d);
    if ((t & 63) == 0) red[t >> 6] = s;
    __syncthreads();
    if (t == 0)
        out_loss[0] = (float)((red[0] + red[1]) / (double)((size_t)N_TOKENS * DIM));
}

extern "C" void kernel_launch(void* const* d_in, const int* in_sizes, int n_in,
                              void* d_out, int out_size, void* d_ws, size_t ws_size,
                              hipStream_t stream)
{
    const float* X = (const float*)d_in[0];   // (32768, 1280) fp32
    const float* E = (const float*)d_in[1];   // (4096, 1280) fp32

    float* outq = (float*)d_out;                       // (32768,1280)
    float* outidx = outq + (size_t)N_TOKENS * DIM;     // (32768,) as float
    float* outloss = outidx + N_TOKENS;                // scalar

    // i8 temps + scales inside outq region (47.3 MB of 167.9 MB); consumed
    // by GEMM, then fully overwritten by refine_gather in-stream.
    signed char* Xq = (signed char*)d_out;                        // 41.9 MB
    signed char* Eq = Xq + (size_t)N_TOKENS * DIM;                // 5.2 MB
    float* sxs = (float*)(Eq + (size_t)N_CODES * DIM);            // 128 KB
    float* ses = sxs + N_TOKENS;                                  // 16 KB

    unsigned* pkeys = (unsigned*)d_ws;                            // 8 MB
    float* sums = (float*)((char*)d_ws + (size_t)N_TOKENS * 64 * sizeof(unsigned));
    double* partial = (double*)(sums + N_TOKENS);                 // 1 KB

    quantize_i8_kernel<<<dim3((N_TOKENS + N_CODES) / 4), dim3(256), 0, stream>>>(
        X, E, Xq, Eq, sxs, ses);
    gemm_argmax_kernel<<<dim3(2048), dim3(1024), 0, stream>>>(Xq, Eq, sxs, ses, pkeys);
    refine_gather_kernel<<<dim3(N_TOKENS / 4), dim3(256), 0, stream>>>(
        X, E, pkeys, outq, outidx, sums);
    loss_partial_kernel<<<dim3(128), dim3(256), 0, stream>>>(sums, partial);
    loss_final_kernel<<<dim3(1), dim3(128), 0, stream>>>(partial, outloss);
}